// Round 11
// baseline (194.385 us; speedup 1.0000x reference)
//
#include <hip/hip_runtime.h>
#include <hip/hip_bf16.h>
#include <stdint.h>

// Problem constants
#define EXP 8
#define DIM 1024
#define SEQL 512
#define BATCH 8
#define OUT_FINAL_N (BATCH * SEQL * DIM)   // 4194304
#define OFF_AUX    4194304
#define OFF_MASK   4194305
#define OFF_LOGITS 4194369

typedef __bf16 bf16_t;
typedef bf16_t bf16x8 __attribute__((ext_vector_type(8)));
typedef bf16_t bf16x4 __attribute__((ext_vector_type(4)));
typedef float  f32x4  __attribute__((ext_vector_type(4)));

typedef __attribute__((address_space(1))) void* as1p;
typedef __attribute__((address_space(3))) void* as3p;

__device__ __forceinline__ void glds16(const void* g, void* l) {
  // async global->LDS, 16B per lane; LDS dest = wave-uniform base + lane*16
  __builtin_amdgcn_global_load_lds((as1p)(void*)g, (as3p)l, 16, 0, 0);
}

// ---------------------------------------------------------------------------
// prep_kernel: fused { w1 transpose-cast | x cast | router }.  (R9 frozen.)
// ---------------------------------------------------------------------------
__global__ __launch_bounds__(256) void prep_kernel(
    const float* __restrict__ x, const float* __restrict__ dec,
    const float* __restrict__ rw, const float* __restrict__ rb,
    const float* __restrict__ w1, const float* __restrict__ w2,
    bf16_t* __restrict__ xb, bf16_t* __restrict__ w1t, bf16_t* __restrict__ w2t,
    float* __restrict__ out_aux, float* __restrict__ out_mask,
    float* __restrict__ out_logits, int* __restrict__ idx_ws,
    float* __restrict__ w_ws) {
  __shared__ __align__(16) char tileb[9216];   // bf16 [64 n][72 k], 144B pitch
  __shared__ float part[256];
  __shared__ float lg64[64];
  __shared__ float probs[64];
  __shared__ float msk[64];
  const int bid = blockIdx.x;
  const int t = threadIdx.x;

  if (bid < 2048) {
    const int z = bid >> 8;
    const int rem = bid & 255;
    const int k0 = (rem >> 4) * 64;
    const int n0 = (rem & 15) * 64;
    const float* src = w1 + (size_t)z * DIM * DIM;
    bf16_t* dst = w1t + (size_t)z * DIM * DIM;
    const int c4 = t & 15;
    const int rr = t >> 4;
    float4 v[4];
#pragma unroll
    for (int r = 0; r < 4; ++r)
      v[r] = *(const float4*)(src + (size_t)(k0 + rr * 4 + r) * DIM + n0 + c4 * 4);
    const float* vp = (const float*)v;
#pragma unroll
    for (int c = 0; c < 4; ++c) {
      bf16x4 o;
#pragma unroll
      for (int jk = 0; jk < 4; ++jk) o[jk] = (bf16_t)vp[jk * 4 + c];
      *(bf16x4*)(tileb + (c4 * 4 + c) * 144 + rr * 8) = o;
    }
    __syncthreads();
#pragma unroll
    for (int ii = 0; ii < 2; ++ii) {
      const int n = (t >> 3) + 32 * ii;
      const int j = t & 7;
      bf16x8 vv = *(const bf16x8*)(tileb + n * 144 + j * 16);
      *(bf16x8*)(dst + (size_t)(n0 + n) * DIM + k0 + j * 8) = vv;
    }
  } else if (bid < 2048 + 512) {
    const int i0 = (bid - 2048) * 2048 + t;
    float4 v[8];
#pragma unroll
    for (int i = 0; i < 8; ++i) v[i] = ((const float4*)x)[i0 + i * 256];
#pragma unroll
    for (int i = 0; i < 8; ++i) {
      bf16x4 o;
      o[0] = (bf16_t)v[i].x; o[1] = (bf16_t)v[i].y;
      o[2] = (bf16_t)v[i].z; o[3] = (bf16_t)v[i].w;
      ((bf16x4*)xb)[i0 + i * 256] = o;
    }
  } else {
    const int p = t >> 2, seg = t & 3;
    const int b = p >> 3, e = p & 7;
    const float4* dv = (const float4*)(dec + b * DIM + seg * 256);
    const float4* wv = (const float4*)(rw + e * DIM + seg * 256);
    float s = 0.f;
#pragma unroll 8
    for (int i = 0; i < 64; ++i) {
      float4 a = dv[i], c = wv[i];
      s += a.x * c.x + a.y * c.y + a.z * c.z + a.w * c.w;
    }
    part[t] = s;
    __syncthreads();
    if (seg == 0) {
      float l = part[t] + part[t + 1] + part[t + 2] + part[t + 3] + rb[e];
      lg64[p] = l;
      out_logits[p] = l;
    }
    __syncthreads();
    if (t < 8) {
      float l[8];
      float mx = -1e30f;
#pragma unroll
      for (int k = 0; k < 8; ++k) { l[k] = lg64[t * 8 + k]; mx = fmaxf(mx, l[k]); }
      float pe[8];
      float sum = 0.f;
#pragma unroll
      for (int k = 0; k < 8; ++k) { pe[k] = expf(l[k] - mx); sum += pe[k]; }
      float inv = 1.f / sum;
#pragma unroll
      for (int k = 0; k < 8; ++k) { pe[k] *= inv; probs[t * 8 + k] = pe[k]; }
      int i0 = 0;
#pragma unroll
      for (int k = 1; k < 8; ++k) if (pe[k] > pe[i0]) i0 = k;
      int i1 = (i0 == 0) ? 1 : 0;
#pragma unroll
      for (int k = 0; k < 8; ++k) if (k != i0 && pe[k] > pe[i1]) i1 = k;
      float p0 = pe[i0], p1 = pe[i1];
      float invs = 1.f / (p0 + p1);
      idx_ws[t * 2] = i0;
      idx_ws[t * 2 + 1] = i1;
      w_ws[t * 2] = p0 * invs;
      w_ws[t * 2 + 1] = p1 * invs;
#pragma unroll
      for (int k = 0; k < 8; ++k) {
        float m = (k == i0 || k == i1) ? 1.f : 0.f;
        msk[t * 8 + k] = m;
        out_mask[t * 8 + k] = m;
      }
    }
    __syncthreads();
    if (t == 0) {
      float aux = 0.f;
#pragma unroll
      for (int k = 0; k < 8; ++k) {
        float mp = 0.f, mm = 0.f;
#pragma unroll
        for (int bb = 0; bb < 8; ++bb) { mp += probs[bb * 8 + k]; mm += msk[bb * 8 + k]; }
        aux += (mp * 0.125f) * (mm * 0.125f);
      }
      out_aux[0] = 8.f * aux;
    }
  }
}

// ---------------------------------------------------------------------------
// GEMM1 (R11 = R10 resubmit): 8-phase 256x256 kernel (T3+T4 full), 512 thr,
// 8 waves (2Mx4N), per-wave 128x64, acc[8][4], BK=64, 2dbuf x 2half = 128KB.
// Audited: vmcnt ledger closes at every phase incl. tail; barriers uniform;
// every STAGE's target half died >=2 barriers earlier; no OOB addresses.
// Stage schedule: ph1:Ah1(d1,2it+1) ph3:Bh0(d0,2it+2) ph4:Bh1+Ah0(d0)
// ph5:Ah1(d0) ph7:Bh0(d1,2it+3) ph8:Bh1+Ah0(d1).  vmcnt(6)@ph4 == all-of-d1
// landed; vmcnt(6)@ph8 == next-d0 landed (in-order retirement).
// LDS swizzle: chunk = (4ks+q) ^ (row&7) -> 2-way banks (free).
// Grid: 128 gemm blocks (T1 XCD swizzle) + 1024 hosted w2-transpose blocks.
// ---------------------------------------------------------------------------
#define BARx() do { asm volatile("" ::: "memory"); __builtin_amdgcn_s_barrier(); asm volatile("" ::: "memory"); } while (0)

#define STAGEA(d, h, kk) do { \
  char* _dst = smem + ((d) * 2 + (h)) * 16384 + tid * 16; \
  const bf16_t* _src = gA + (size_t)((h) * 128) * DIM + (kk) * 64; \
  glds16(_src, _dst); glds16(_src + (size_t)64 * DIM, _dst + 8192); } while (0)

#define STAGEB(d, h, kk) do { \
  char* _dst = smem + 65536 + ((d) * 2 + (h)) * 16384 + tid * 16; \
  const bf16_t* _src = gB + (size_t)((h) * 128) * DIM + (kk) * 64; \
  glds16(_src, _dst); glds16(_src + (size_t)64 * DIM, _dst + 8192); } while (0)

#define LOADA(d, mh) do { \
  const char* _ba = smem + ((d) * 2 + wr) * 16384 + (mh) * 8192; \
  _Pragma("unroll") for (int _il = 0; _il < 4; ++_il) { \
    af[_il][0] = *(const bf16x8*)(_ba + _il * 2048 + abase0); \
    af[_il][1] = *(const bf16x8*)(_ba + _il * 2048 + abase1); } } while (0)

#define LOADB(d, nh) do { \
  const char* _bb = smem + 65536 + ((d) * 2 + (wc >> 1)) * 16384; \
  _Pragma("unroll") for (int _jl = 0; _jl < 2; ++_jl) { \
    bfr[(nh) * 2 + _jl][0] = *(const bf16x8*)(_bb + ((nh) * 2 + _jl) * 2048 + bbase0); \
    bfr[(nh) * 2 + _jl][1] = *(const bf16x8*)(_bb + ((nh) * 2 + _jl) * 2048 + bbase1); } } while (0)

#define MMAQ(mh, nh) do { __builtin_amdgcn_s_setprio(1); \
  _Pragma("unroll") for (int _il = 0; _il < 4; ++_il) \
  _Pragma("unroll") for (int _jl = 0; _jl < 2; ++_jl) { \
    acc[(mh) * 4 + _il][(nh) * 2 + _jl] = __builtin_amdgcn_mfma_f32_16x16x32_bf16( \
        af[_il][0], bfr[(nh) * 2 + _jl][0], acc[(mh) * 4 + _il][(nh) * 2 + _jl], 0, 0, 0); \
    acc[(mh) * 4 + _il][(nh) * 2 + _jl] = __builtin_amdgcn_mfma_f32_16x16x32_bf16( \
        af[_il][1], bfr[(nh) * 2 + _jl][1], acc[(mh) * 4 + _il][(nh) * 2 + _jl], 0, 0, 0); } \
  __builtin_amdgcn_s_setprio(0); } while (0)

__global__ __launch_bounds__(512, 2) void gemm1_kernel(const bf16_t* __restrict__ xb,
                                                       const bf16_t* __restrict__ w1t,
                                                       const float* __restrict__ b1,
                                                       const int* __restrict__ topk_idx,
                                                       bf16_t* __restrict__ hidden,
                                                       const float* __restrict__ w2,
                                                       bf16_t* __restrict__ w2t) {
  __shared__ __align__(16) char smem[131072];  // A: 2d x 2h x 16KB | B: same
  const int bid = blockIdx.x;
  const int tid = threadIdx.x;

  if (bid >= 128) {
    // ---- hosted w2 transpose (R7-passed body): 2 halves x 1 tile ----
    const int half = tid >> 8;
    const int tt = tid & 255;
    char* tb = smem + half * 9216;
    const int tile = (bid - 128) * 2 + half;     // 0..2047
    const int z = tile >> 8;
    const int rem = tile & 255;
    const int k0 = (rem >> 4) * 64;
    const int n0 = (rem & 15) * 64;
    const float* src = w2 + (size_t)z * DIM * DIM;
    bf16_t* dst = w2t + (size_t)z * DIM * DIM;
    const int c4 = tt & 15;
    const int rr = tt >> 4;
    float4 v[4];
#pragma unroll
    for (int r = 0; r < 4; ++r)
      v[r] = *(const float4*)(src + (size_t)(k0 + rr * 4 + r) * DIM + n0 + c4 * 4);
    const float* vp = (const float*)v;
#pragma unroll
    for (int c = 0; c < 4; ++c) {
      bf16x4 o;
#pragma unroll
      for (int jk = 0; jk < 4; ++jk) o[jk] = (bf16_t)vp[jk * 4 + c];
      *(bf16x4*)(tb + (c4 * 4 + c) * 144 + rr * 8) = o;
    }
    __syncthreads();
#pragma unroll
    for (int ii = 0; ii < 2; ++ii) {
      const int n = (tt >> 3) + 32 * ii;
      const int j = tt & 7;
      bf16x8 vv = *(const bf16x8*)(tb + n * 144 + j * 16);
      *(bf16x8*)(dst + (size_t)(n0 + n) * DIM + k0 + j * 8) = vv;
    }
    return;
  }

  // ---- gemm: T1 XCD swizzle (128 = 8 x 16), decode bN fastest ----
  const int wgid = (bid & 7) * 16 + (bid >> 3);
  const int bN = wgid & 3, bM = (wgid >> 2) & 1, slot = wgid >> 3;
  const int b = slot >> 1;
  const int e = topk_idx[slot];

  const bf16_t* A  = xb + ((size_t)b * SEQL + bM * 256) * DIM;
  const bf16_t* Bt = w1t + ((size_t)e * DIM + bN * 256) * DIM;

  // staging addresses (3-bit pre-swizzled chunk)
  const int srow = tid >> 3;                    // 0..63
  const int sc = (tid & 7) ^ (srow & 7);        // chunk 0..7
  const bf16_t* gA = A + (size_t)srow * DIM + sc * 8;
  const bf16_t* gB = Bt + (size_t)srow * DIM + sc * 8;

  // wave geometry: 8 waves = 2M x 4N; per-wave 128 rows x 64 cols
  const int lane = tid & 63, w = tid >> 6;
  const int wr = w >> 2, wc = w & 3;
  const int m15 = lane & 15, q = lane >> 4;
  const int abase0 = m15 * 128 + ((q ^ (m15 & 7)) * 16);            // ks=0
  const int abase1 = m15 * 128 + (((4 + q) ^ (m15 & 7)) * 16);      // ks=1
  const int bbase0 = (wc & 1) * 8192 + abase0;
  const int bbase1 = (wc & 1) * 8192 + abase1;

  f32x4 acc[8][4];
#pragma unroll
  for (int i = 0; i < 8; ++i)
#pragma unroll
    for (int j = 0; j < 4; ++j) acc[i][j] = {0.f, 0.f, 0.f, 0.f};
  bf16x8 af[4][2], bfr[4][2];

  // prologue: K0 full (8 loads) + K1's Bh0,Bh1,Ah0 (6 loads); vmcnt(6)
  // forces exactly the first 8 (= all of K0) before ph1 reads d0.
  STAGEB(0, 0, 0); STAGEB(0, 1, 0); STAGEA(0, 0, 0); STAGEA(0, 1, 0);
  STAGEB(1, 0, 1); STAGEB(1, 1, 1); STAGEA(1, 0, 1);
  asm volatile("s_waitcnt vmcnt(6)" ::: "memory");
  __builtin_amdgcn_s_barrier();
  asm volatile("" ::: "memory");

  for (int it = 0; it < 8; ++it) {
    const int k1 = 2 * it + 1, k2 = 2 * it + 2, k3 = 2 * it + 3;
    // ph1: quadrant (0,0) of d0
    LOADA(0, 0); LOADB(0, 0);
    STAGEA(1, 1, k1);                       // completes d1 for ph5-8
    BARx(); MMAQ(0, 0); BARx();
    // ph2: (0,1)
    LOADB(0, 1);
    BARx(); MMAQ(0, 1); BARx();
    // ph3: (1,1)   [B(d0) died end-ph2]
    LOADA(0, 1);
    if (it < 7) STAGEB(0, 0, k2);
    BARx(); MMAQ(1, 1); BARx();
    // ph4: (1,0)   [A(d0) died end-ph3]; vmcnt forces all-of-d1 landed
    if (it < 7) { STAGEB(0, 1, k2); STAGEA(0, 0, k2); }
    BARx(); MMAQ(1, 0);
    if (it < 7) { asm volatile("s_waitcnt vmcnt(6)" ::: "memory"); }
    else        { asm volatile("s_waitcnt vmcnt(0)" ::: "memory"); }
    BARx();
    // ph5: (0,0) of d1
    LOADA(1, 0); LOADB(1, 0);
    if (it < 7) STAGEA(0, 1, k2);
    BARx(); MMAQ(0, 0); BARx();
    // ph6: (0,1)
    LOADB(1, 1);
    BARx(); MMAQ(0, 1); BARx();
    // ph7: (1,1)   [B(d1) died end-ph6]
    LOADA(1, 1);
    if (it < 7) STAGEB(1, 0, k3);
    BARx(); MMAQ(1, 1); BARx();
    // ph8: (1,0)   [A(d1) died end-ph7]; vmcnt forces next-d0 landed
    if (it < 7) { STAGEB(1, 1, k3); STAGEA(1, 0, k3); }
    BARx(); MMAQ(1, 0);
    if (it < 7) { asm volatile("s_waitcnt vmcnt(6)" ::: "memory"); }
    BARx();
  }

  // epilogue: bias + relu + cast; two 128-row chunks bounced through LDS.
  // C/D layout: col = lane&15, row = quad*4 + reg (m89-verified).
  const float* be = b1 + e * DIM;
#pragma unroll
  for (int mchunk = 0; mchunk < 2; ++mchunk) {
    __syncthreads();
    bf16_t* hb = (bf16_t*)smem;              // [128][264] halfwords
    if (wr == mchunk) {
#pragma unroll
      for (int fi = 0; fi < 8; ++fi)
#pragma unroll
        for (int fj = 0; fj < 4; ++fj) {
          const int colL = wc * 64 + fj * 16 + m15;
          const float bias = be[bN * 256 + colL];
#pragma unroll
          for (int r = 0; r < 4; ++r) {
            const int rowL = fi * 16 + q * 4 + r;
            hb[rowL * 264 + colL] = (bf16_t)fmaxf(acc[fi][fj][r] + bias, 0.f);
          }
        }
    }
    __syncthreads();
    bf16_t* H = hidden + (size_t)slot * SEQL * DIM +
                (size_t)(bM * 256 + mchunk * 128) * DIM + bN * 256;
#pragma unroll
    for (int ii = 0; ii < 8; ++ii) {
      const int rr_ = (tid >> 5) + ii * 16;  // 0..127
      const int cc_ = (tid & 31) * 8;        // 0..248
      bf16x8 vv = *(const bf16x8*)(hb + rr_ * 264 + cc_);
      *(bf16x8*)(H + (size_t)rr_ * DIM + cc_) = vv;
    }
  }
}

// ---------------------------------------------------------------------------
// GEMM2 (R9 frozen, passed): paired-group 512-thr, 3-buffer depth-2,
// counted vmcnt(4), T1 swizzle.  grid 1-D 256 blocks.
// ---------------------------------------------------------------------------
__global__ __launch_bounds__(512, 2) void gemm2_kernel(const bf16_t* __restrict__ hidden,
                                                       const bf16_t* __restrict__ w2t,
                                                       const float* __restrict__ b2,
                                                       const int* __restrict__ topk_idx,
                                                       const float* __restrict__ topk_w,
                                                       float* __restrict__ out) {
  __shared__ __align__(16) char smem2[98304];   // per group: sA 3x8K | sB 3x8K
  const int tid = threadIdx.x;
  const int g = tid >> 8;
  const int t = tid & 255;
  const int raw = blockIdx.x;
  const int wg = (raw & 7) * 32 + (raw >> 3);
  const int bN = wg & 7, bM = (wg >> 3) & 3, b = wg >> 5;
  const int slot = b * 2 + g;
  const int e = topk_idx[slot];
  const float sg = topk_w[slot];

  const bf16_t* A  = hidden + ((size_t)slot * SEQL + bM * 128) * DIM;
  const bf16_t* Bt = w2t + ((size_t)e * DIM + bN * 128) * DIM;

  char* sA = smem2 + g * 49152;
  char* sB = sA + 24576;

  const int rl = t >> 2, cp = (t & 3) ^ (rl & 3);          // rows 0..63
  const bf16_t* gA0 = A + (size_t)rl * DIM + cp * 8;
  const bf16_t* gA1 = gA0 + (size_t)64 * DIM;
  const bf16_t* gB0 = Bt + (size_t)rl * DIM + cp * 8;
  const bf16_t* gB1 = gB0 + (size_t)64 * DIM;

  const int lane = tid & 63, wgv = (tid >> 6) & 3;
  const int wr = wgv >> 1, wc = wgv & 1;
  const int m15 = lane & 15, q = lane >> 4;
  const char* ra[4];
  const char* rb[4];
#pragma unroll
  for (int i = 0; i < 4; ++i) {
    const int r = wr * 64 + i * 16 + m15;
    ra[i] = sA + r * 64 + ((q ^ (r & 3)) * 16);
    const int n = wc * 64 + i * 16 + m15;
    rb[i] = sB + n * 64 + ((q ^ (n & 3)) * 16);
  }

  f32x4 acc[4][4];
#pragma unroll
  for (int i = 0; i < 4; ++i)
#pragma unroll
    for (int j = 0; j < 4; ++j) acc[i][j] = {0.f, 0.f, 0.f, 0.f};

  glds16(gA0, sA + t * 16);
  glds16(gA1, sA + 4096 + t * 16);
  glds16(gB0, sB + t * 16);
  glds16(gB1, sB + 4096 + t * 16);
  glds16(gA0 + 32, sA + 8192 + t * 16);
  glds16(gA1 + 32, sA + 8192 + 4096 + t * 16);
  glds16(gB0 + 32, sB + 8192 + t * 16);
  glds16(gB1 + 32, sB + 8192 + 4096 + t * 16);

  int cur = 0;
  for (int kt = 0; kt < 32; ++kt) {
    if (kt < 31) {
      asm volatile("s_waitcnt vmcnt(4)" ::: "memory");
    } else {
      asm volatile("s_waitcnt vmcnt(0)" ::: "memory");
    }
    __builtin_amdgcn_s_barrier();
    asm volatile("" ::: "memory");
    if (kt < 30) {
      int nb = cur + 2; if (nb >= 3) nb -= 3;
      const int off = (kt + 2) * 32;
      char* dA = sA + nb * 8192 + t * 16;
      char* dB = sB + nb * 8192 + t * 16;
      glds16(gA0 + off, dA);
      glds16(gA1 + off, dA + 4096);
      glds16(gB0 + off, dB);
      glds16(gB1 + off, dB + 4096);
    }
    bf16x8 af2[4], bfr2[4];
#pragma unroll
    for (int i = 0; i < 4; ++i) af2[i] = *(const bf16x8*)(ra[i] + cur * 8192);
#pragma unroll
    for (int j = 0; j < 4; ++j) bfr2[j] = *(const bf16x8*)(rb[j] + cur * 8192);
    __builtin_amdgcn_s_setprio(1);
#pragma unroll
    for (int i = 0; i < 4; ++i)
#pragma unroll
      for (int j = 0; j < 4; ++j)
        acc[i][j] = __builtin_amdgcn_mfma_f32_16x16x32_bf16(af2[i], bfr2[j], acc[i][j], 0, 0, 0);
    __builtin_amdgcn_s_setprio(0);
    cur += 1; if (cur == 3) cur = 0;
  }

  __syncthreads();
  float* scr = (float*)smem2;
  const float w0 = topk_w[b * 2], w1v = topk_w[b * 2 + 1];
  const float* be0 = b2 + topk_idx[b * 2] * DIM;
  const float* be1 = b2 + topk_idx[b * 2 + 1] * DIM;
  float* O = out + (size_t)b * SEQL * DIM;
#pragma unroll
  for (int i = 0; i < 4; ++i) {
    if (g == 1) {
#pragma unroll
      for (int j = 0; j < 4; ++j)
#pragma unroll
        for (int r = 0; r < 4; ++r)
          scr[(j * 4 + r) * 256 + t] = sg * acc[i][j][r];
    }
    __syncthreads();
    if (g == 0) {
#pragma unroll
      for (int j = 0; j < 4; ++j) {
        const int col = bN * 128 + wc * 64 + j * 16 + m15;
        const float bb = w0 * be0[col] + w1v * be1[col];
        const int row = bM * 128 + wr * 64 + i * 16 + q * 4;
#pragma unroll
        for (int r = 0; r < 4; ++r)
          O[(size_t)(row + r) * DIM + col] =
              sg * acc[i][j][r] + scr[(j * 4 + r) * 256 + t] + bb;
      }
    }
    __syncthreads();
  }
}

// ---------------------------------------------------------------------------
extern "C" void kernel_launch(void* const* d_in, const int* in_sizes, int n_in,
                              void* d_out, int out_size, void* d_ws, size_t ws_size,
                              hipStream_t stream) {
  const float* x   = (const float*)d_in[0];
  const float* dec = (const float*)d_in[1];
  const float* rw  = (const float*)d_in[2];
  const float* rb  = (const float*)d_in[3];
  const float* w1  = (const float*)d_in[4];
  const float* w2  = (const float*)d_in[5];
  const float* b1  = (const float*)d_in[6];
  const float* b2  = (const float*)d_in[7];
  float* out = (float*)d_out;

  // ws layout: xb 8MB | w1t 16MB | w2t 16MB | hidden 16MB | router scratch
  char* ws = (char*)d_ws;
  bf16_t* xb   = (bf16_t*)(ws);
  bf16_t* w1t  = (bf16_t*)(ws + (8u << 20));
  bf16_t* w2t  = (bf16_t*)(ws + (24u << 20));
  bf16_t* hid  = (bf16_t*)(ws + (40u << 20));
  int*    idxw = (int*)(ws + (56u << 20));
  float*  ww   = (float*)(ws + (56u << 20) + 64);

  hipLaunchKernelGGL(prep_kernel, dim3(2048 + 512 + 1), dim3(256), 0, stream,
                     x, dec, rw, rb, w1, w2, xb, w1t, w2t,
                     out + OFF_AUX, out + OFF_MASK, out + OFF_LOGITS, idxw, ww);
  hipLaunchKernelGGL(gemm1_kernel, dim3(128 + 1024), dim3(512), 0, stream,
                     xb, w1t, b1, idxw, hid, w2, w2t);
  hipLaunchKernelGGL(gemm2_kernel, dim3(256), dim3(512), 0, stream,
                     hid, w2t, b2, idxw, ww, out);
}